// Round 2
// baseline (1427.594 us; speedup 1.0000x reference)
//
#include <hip/hip_runtime.h>
#include <math.h>

typedef __bf16 bf16x8 __attribute__((ext_vector_type(8)));
typedef float f32x4 __attribute__((ext_vector_type(4)));

// fp32 -> bf16 (round-to-nearest-even), element
__device__ __forceinline__ __bf16 f2bf(float f) {
    union { float f; unsigned u; } v; v.f = f;
    unsigned r = v.u + 0x7FFF + ((v.u >> 16) & 1);
    union { unsigned short s; __bf16 b; } c; c.s = (unsigned short)(r >> 16);
    return c.b;
}

// load 8 consecutive fp32, convert to bf16x8 fragment
__device__ __forceinline__ bf16x8 ld8(const float* p) {
    f32x4 lo = *reinterpret_cast<const f32x4*>(p);
    f32x4 hi = *reinterpret_cast<const f32x4*>(p + 4);
    bf16x8 r;
#pragma unroll
    for (int i = 0; i < 4; ++i) { r[i] = f2bf(lo[i]); r[i + 4] = f2bf(hi[i]); }
    return r;
}

// ---------------------------------------------------------------------------
// Generic M=64 GEMM:  out[m,n] = epilogue( sum_k A[m,k]*W[n,k] + bias[n] )
// A: [64,K] fp32 row-major, W: [N,K] fp32 row-major (computes A @ W.T).
// One wave per block; block computes 16 columns x 64 rows via 16x16x32 MFMA.
// A-frag: lane holds A[(lane&15)+16*mt][quad*8 ..+7]; B-frag: W[n0+(lane&15)][quad*8..+7]
// C/D: col = lane&15 (n), row = quad*4 + reg (m within 16-tile).
// MODE 0: out = acc + bias;  MODE 1: out = relu(acc+bias);
// MODE 2: out = relu(acc+bias) + resid[m,n]
// blockIdx.y = layer (batched); strides in elements.
// ---------------------------------------------------------------------------
template <int MODE>
__global__ __launch_bounds__(64) void gemm16(
    const float* __restrict__ A, long long Asb,
    const float* __restrict__ W, long long Wsb,
    const float* __restrict__ bias, long long bsb,
    float* __restrict__ out, long long osb,
    const float* __restrict__ resid, int K, int N)
{
    const int l = threadIdx.x;
    const int lane16 = l & 15;
    const int quad = l >> 4;
    const int layer = blockIdx.y;
    const int n = blockIdx.x * 16 + lane16;

    A += (long long)layer * Asb;
    W += (long long)layer * Wsb;

    const float* wp  = W + (long long)n * K + quad * 8;
    const float* ap0 = A + (long long)(lane16 + 0) * K + quad * 8;
    const float* ap1 = A + (long long)(lane16 + 16) * K + quad * 8;
    const float* ap2 = A + (long long)(lane16 + 32) * K + quad * 8;
    const float* ap3 = A + (long long)(lane16 + 48) * K + quad * 8;

    f32x4 acc0 = {0.f, 0.f, 0.f, 0.f};
    f32x4 acc1 = acc0, acc2 = acc0, acc3 = acc0;

    for (int k = 0; k < K; k += 32) {
        bf16x8 b  = ld8(wp + k);
        bf16x8 a0 = ld8(ap0 + k);
        bf16x8 a1 = ld8(ap1 + k);
        bf16x8 a2 = ld8(ap2 + k);
        bf16x8 a3 = ld8(ap3 + k);
        acc0 = __builtin_amdgcn_mfma_f32_16x16x32_bf16(a0, b, acc0, 0, 0, 0);
        acc1 = __builtin_amdgcn_mfma_f32_16x16x32_bf16(a1, b, acc1, 0, 0, 0);
        acc2 = __builtin_amdgcn_mfma_f32_16x16x32_bf16(a2, b, acc2, 0, 0, 0);
        acc3 = __builtin_amdgcn_mfma_f32_16x16x32_bf16(a3, b, acc3, 0, 0, 0);
    }

    const float bv = bias[(long long)layer * bsb + n];
    f32x4 accs[4] = {acc0, acc1, acc2, acc3};
#pragma unroll
    for (int mt = 0; mt < 4; ++mt) {
#pragma unroll
        for (int r = 0; r < 4; ++r) {
            const int m = mt * 16 + quad * 4 + r;
            float v = accs[mt][r] + bv;
            const long long oidx = (long long)layer * osb + (long long)m * N + n;
            if (MODE >= 1) v = fmaxf(v, 0.0f);
            if (MODE == 2) v += resid[(long long)m * N + n];
            out[oidx] = v;
        }
    }
}

// xe = relu(emb[x])  -> [64,1024] fp32
__global__ __launch_bounds__(256) void gather_relu(
    const float* __restrict__ emb, const int* __restrict__ xidx,
    float* __restrict__ xe)
{
    const int gid = blockIdx.x * 256 + threadIdx.x;  // 65536 total
    const int m = gid >> 10, e = gid & 1023;
    xe[gid] = fmaxf(emb[(long long)xidx[m] * 1024 + e], 0.0f);
}

// h[i] = hiddens[i] + attn  -> [8,64,1024] fp32
__global__ __launch_bounds__(256) void hsum(
    const float* __restrict__ hiddens, const float* __restrict__ attn,
    float* __restrict__ h)
{
    const int gid = blockIdx.x * 256 + threadIdx.x;  // 524288 total
    h[gid] = hiddens[gid] + attn[gid & 65535];
}

// GRU pointwise; writes cell output (and h1 copy for c==0) and next input
// xin_next = o (+ oprev for the skip-sum cells)
__global__ __launch_bounds__(256) void gru_pw(
    const float* __restrict__ gi, const float* __restrict__ gh,
    const float* __restrict__ h, const float* __restrict__ oprev,
    float* __restrict__ o_out, float* __restrict__ o_out2,
    float* __restrict__ xin_next)
{
    const int gid = blockIdx.x * 256 + threadIdx.x;  // 65536 total
    const int m = gid >> 10, nn = gid & 1023;
    const long long gb = (long long)m * 3072 + nn;
    const float i_r = gi[gb], i_z = gi[gb + 1024], i_n = gi[gb + 2048];
    const float h_r = gh[gb], h_z = gh[gb + 1024], h_n = gh[gb + 2048];
    const float r = 1.0f / (1.0f + __expf(-(i_r + h_r)));
    const float z = 1.0f / (1.0f + __expf(-(i_z + h_z)));
    const float nv = tanhf(i_n + r * h_n);
    const float x = (1.0f - z) * nv + z * h[gid];
    o_out[gid] = x;
    if (o_out2) o_out2[gid] = x;
    float xi = x;
    if (oprev) xi += oprev[gid];
    xin_next[gid] = xi;
}

// per-row logsumexp over [64,32000] fp32 logits (in d_out)
__global__ __launch_bounds__(256) void rowstats(
    const float* __restrict__ logits, float* __restrict__ stats)
{
    const int m = blockIdx.x;
    const float* row = logits + (long long)m * 32000;
    __shared__ float red[256];
    const int tid = threadIdx.x;
    float mx = -1e30f;
    for (int n = tid; n < 32000; n += 256) mx = fmaxf(mx, row[n]);
    red[tid] = mx;
    __syncthreads();
    for (int off = 128; off > 0; off >>= 1) {
        if (tid < off) red[tid] = fmaxf(red[tid], red[tid + off]);
        __syncthreads();
    }
    mx = red[0];
    __syncthreads();
    float s = 0.0f;
    for (int n = tid; n < 32000; n += 256) s += __expf(row[n] - mx);
    red[tid] = s;
    __syncthreads();
    for (int off = 128; off > 0; off >>= 1) {
        if (tid < off) red[tid] += red[tid + off];
        __syncthreads();
    }
    if (tid == 0) stats[m] = mx + logf(red[0]);
}

// in-place: logp = logits - stats[m]
__global__ __launch_bounds__(256) void logp_k(
    float* __restrict__ out, const float* __restrict__ stats)
{
    const int n = blockIdx.x * 256 + threadIdx.x;  // gridDim.x = 125
    const int m = blockIdx.y;
    const long long idx = (long long)m * 32000 + n;
    out[idx] = out[idx] - stats[m];
}

extern "C" void kernel_launch(void* const* d_in, const int* in_sizes, int n_in,
                              void* d_out, int out_size, void* d_ws, size_t ws_size,
                              hipStream_t stream)
{
    const float* feature   = (const float*)d_in[0];   // [64,2048]
    const int*   x         = (const int*)d_in[1];     // [64]
    const float* attention = (const float*)d_in[2];   // [64,1024]
    const float* hiddens   = (const float*)d_in[3];   // [8,64,1024]
    const float* emb       = (const float*)d_in[4];   // [32000,1024]
    const float* map_W     = (const float*)d_in[5];   // [1024,2048]
    const float* map_b     = (const float*)d_in[6];
    const float* ai_W      = (const float*)d_in[7];
    const float* ai_b      = (const float*)d_in[8];
    const float* ah_W      = (const float*)d_in[9];
    const float* ah_b      = (const float*)d_in[10];
    const float* ao_W      = (const float*)d_in[11];
    const float* ao_b      = (const float*)d_in[12];
    const float* gru_Wih   = (const float*)d_in[13];  // [8,3072,1024]
    const float* gru_Whh   = (const float*)d_in[14];  // [8,3072,1024]
    const float* gru_bih   = (const float*)d_in[15];  // [8,3072]
    const float* gru_bhh   = (const float*)d_in[16];  // [8,3072]
    const float* out_W     = (const float*)d_in[17];  // [32000,1024]
    const float* out_b     = (const float*)d_in[18];  // [32000]

    float* out      = (float*)d_out;
    float* out_logp = out;                    // [64,32000]
    float* out_h1   = out + 2048000;          // [64,1024]
    float* out_nh   = out + 2048000 + 65536;  // [8,64,1024]

    char* w = (char*)d_ws;
    float* xin   = (float*)(w + 0);         // 262144 B  [64,1024]
    float* t0    = (float*)(w + 262144);    // 262144 B
    float* a1b   = (float*)(w + 524288);    // 262144 B
    float* a2b   = (float*)(w + 786432);    // 262144 B
    float* attnb = (float*)(w + 1048576);   // 262144 B
    float* hbuf  = (float*)(w + 1310720);   // 2097152 B [8,64,1024]
    float* gh    = (float*)(w + 3407872);   // 6291456 B [8,64,3072]
    float* gi    = (float*)(w + 9699328);   // 786432 B  [64,3072]
    float* stats = (float*)(w + 10485760);  // 256 B

    // xe = relu(emb[x])
    gather_relu<<<256, 256, 0, stream>>>(emb, x, xin);

    // t0 = relu(feature @ map_W.T + map_b) + attention
    gemm16<2><<<dim3(64, 1), 64, 0, stream>>>(feature, 0, map_W, 0, map_b, 0,
                                              t0, 0, attention, 2048, 1024);
    // attn chain
    gemm16<1><<<dim3(64, 1), 64, 0, stream>>>(t0, 0, ai_W, 0, ai_b, 0,
                                              a1b, 0, nullptr, 1024, 1024);
    gemm16<1><<<dim3(64, 1), 64, 0, stream>>>(a1b, 0, ah_W, 0, ah_b, 0,
                                              a2b, 0, nullptr, 1024, 1024);
    gemm16<1><<<dim3(64, 1), 64, 0, stream>>>(a2b, 0, ao_W, 0, ao_b, 0,
                                              attnb, 0, nullptr, 1024, 1024);

    // h[i] = hiddens[i] + attn
    hsum<<<2048, 256, 0, stream>>>(hiddens, attnb, hbuf);

    // batched gh[i] = h[i] @ Whh[i].T + bhh[i]
    gemm16<0><<<dim3(192, 8), 64, 0, stream>>>(hbuf, 65536, gru_Whh, 3145728,
                                               gru_bhh, 3072, gh, 196608,
                                               nullptr, 1024, 3072);

    // sequential GRU chain
    for (int c = 0; c < 8; ++c) {
        gemm16<0><<<dim3(192, 1), 64, 0, stream>>>(
            xin, 0, gru_Wih + (long long)c * 3145728, 0, gru_bih + c * 3072, 0,
            gi, 0, nullptr, 1024, 3072);
        gru_pw<<<256, 256, 0, stream>>>(
            gi, gh + (long long)c * 196608, hbuf + (long long)c * 65536,
            (c >= 2) ? out_nh + (long long)(c - 1) * 65536 : nullptr,
            out_nh + (long long)c * 65536,
            (c == 0) ? out_h1 : nullptr,
            xin);
    }

    // logits = x8 @ out_W.T + out_b  (written into the logp region of d_out)
    gemm16<0><<<dim3(2000, 1), 64, 0, stream>>>(out_nh + 7LL * 65536, 0, out_W, 0,
                                                out_b, 0, out_logp, 0,
                                                nullptr, 1024, 32000);

    // log_softmax in place
    rowstats<<<64, 256, 0, stream>>>(out_logp, stats);
    logp_k<<<dim3(125, 64), 256, 0, stream>>>(out_logp, stats);
}

// Round 4
// 691.857 us; speedup vs baseline: 2.0634x; 2.0634x over previous
//
#include <hip/hip_runtime.h>
#include <math.h>

typedef __bf16 bf16x8 __attribute__((ext_vector_type(8)));
typedef float f32x4 __attribute__((ext_vector_type(4)));

// fp32 -> bf16 (round-to-nearest-even), element
__device__ __forceinline__ __bf16 f2bf(float f) {
    union { float f; unsigned u; } v; v.f = f;
    unsigned r = v.u + 0x7FFF + ((v.u >> 16) & 1);
    union { unsigned short s; __bf16 b; } c; c.s = (unsigned short)(r >> 16);
    return c.b;
}

// load 8 consecutive fp32 (-> optional relu) -> bf16x8 fragment
template <int RELU>
__device__ __forceinline__ bf16x8 ld8(const float* p) {
    f32x4 lo = *reinterpret_cast<const f32x4*>(p);
    f32x4 hi = *reinterpret_cast<const f32x4*>(p + 4);
    bf16x8 r;
#pragma unroll
    for (int i = 0; i < 4; ++i) {
        float a = lo[i], b = hi[i];
        if (RELU) { a = fmaxf(a, 0.0f); b = fmaxf(b, 0.0f); }
        r[i] = f2bf(a); r[i + 4] = f2bf(b);
    }
    return r;
}

// relu(A) + resid, both 8 consecutive fp32 -> bf16x8
__device__ __forceinline__ bf16x8 ld8ra(const float* p, const float* rp) {
    f32x4 lo = *reinterpret_cast<const f32x4*>(p);
    f32x4 hi = *reinterpret_cast<const f32x4*>(p + 4);
    f32x4 rl = *reinterpret_cast<const f32x4*>(rp);
    f32x4 rh = *reinterpret_cast<const f32x4*>(rp + 4);
    bf16x8 r;
#pragma unroll
    for (int i = 0; i < 4; ++i) {
        r[i]     = f2bf(fmaxf(lo[i], 0.0f) + rl[i]);
        r[i + 4] = f2bf(fmaxf(hi[i], 0.0f) + rh[i]);
    }
    return r;
}

__device__ __forceinline__ void atomAdd(float* p, float v) {
#if __has_builtin(__builtin_amdgcn_global_atomic_fadd_f32)
    unsafeAtomicAdd(p, v);
#else
    atomicAdd(p, v);
#endif
}

// ---------------------------------------------------------------------------
// K-split accumulating GEMM:  out[m,n] += sum_{k in chunk} A'[m,k]*W[n,k]
// MODE_A: 0 -> A' = A; 1 -> A' = relu(A); 2 -> A' = relu(A) + Ares
// A: [64,K] fp32 row-major, W: [N,K] fp32 row-major (computes A' @ W.T).
// out must be pre-initialized (bias) by the init kernel.
// grid = (N/16 n-tiles, K/KC k-chunks, layers); one wave per block.
// MFMA 16x16x32 bf16; C/D: col = lane&15 (n), row = quad*4 + reg.
// ---------------------------------------------------------------------------
template <int MODE_A>
__global__ __launch_bounds__(64) void gemm_acc(
    const float* __restrict__ A, long long Asb,
    const float* __restrict__ W, long long Wsb,
    const float* __restrict__ Ares,
    float* __restrict__ out, long long osb,
    int K, int KC, int N)
{
    const int l = threadIdx.x;
    const int lane16 = l & 15;
    const int quad = l >> 4;
    const int layer = blockIdx.z;
    const int n = blockIdx.x * 16 + lane16;
    const int k0 = blockIdx.y * KC;

    A += (long long)layer * Asb + k0 + quad * 8;
    W += (long long)layer * Wsb + k0 + quad * 8;
    if (MODE_A == 2) Ares += k0 + quad * 8;

    const float* wp  = W + (long long)n * K;
    const float* ap0 = A + (long long)(lane16 + 0) * K;
    const float* ap1 = A + (long long)(lane16 + 16) * K;
    const float* ap2 = A + (long long)(lane16 + 32) * K;
    const float* ap3 = A + (long long)(lane16 + 48) * K;
    const float* rp0 = Ares + (long long)(lane16 + 0) * K;
    const float* rp1 = Ares + (long long)(lane16 + 16) * K;
    const float* rp2 = Ares + (long long)(lane16 + 32) * K;
    const float* rp3 = Ares + (long long)(lane16 + 48) * K;

    f32x4 acc0 = {0.f, 0.f, 0.f, 0.f};
    f32x4 acc1 = acc0, acc2 = acc0, acc3 = acc0;

#pragma unroll 4
    for (int k = 0; k < KC; k += 32) {
        bf16x8 b = ld8<0>(wp + k);
        bf16x8 a0, a1, a2, a3;
        if (MODE_A == 2) {
            a0 = ld8ra(ap0 + k, rp0 + k);
            a1 = ld8ra(ap1 + k, rp1 + k);
            a2 = ld8ra(ap2 + k, rp2 + k);
            a3 = ld8ra(ap3 + k, rp3 + k);
        } else {
            a0 = ld8<MODE_A>(ap0 + k);
            a1 = ld8<MODE_A>(ap1 + k);
            a2 = ld8<MODE_A>(ap2 + k);
            a3 = ld8<MODE_A>(ap3 + k);
        }
        acc0 = __builtin_amdgcn_mfma_f32_16x16x32_bf16(a0, b, acc0, 0, 0, 0);
        acc1 = __builtin_amdgcn_mfma_f32_16x16x32_bf16(a1, b, acc1, 0, 0, 0);
        acc2 = __builtin_amdgcn_mfma_f32_16x16x32_bf16(a2, b, acc2, 0, 0, 0);
        acc3 = __builtin_amdgcn_mfma_f32_16x16x32_bf16(a3, b, acc3, 0, 0, 0);
    }

    f32x4 accs[4] = {acc0, acc1, acc2, acc3};
    float* ob = out + (long long)layer * osb + n;
#pragma unroll
    for (int mt = 0; mt < 4; ++mt)
#pragma unroll
        for (int r = 0; r < 4; ++r) {
            const int m = mt * 16 + quad * 4 + r;
            atomAdd(ob + (long long)m * N, accs[mt][r]);
        }
}

// Pre-initialize all fp32 accumulators with biases.
// Ranges (in elems): t0 64x1024 | a1b | a2b | attnb | gh 8x64x3072 |
//                    gi 8x64x3072 | logp 64x32000
__global__ __launch_bounds__(256) void init_acc(
    const float* __restrict__ map_b,
    const float* __restrict__ ai_b, const float* __restrict__ ah_b,
    const float* __restrict__ ao_b, const float* __restrict__ gru_bhh,
    const float* __restrict__ gru_bih, const float* __restrict__ out_b,
    float* __restrict__ t0, float* __restrict__ a1b, float* __restrict__ a2b,
    float* __restrict__ attnb, float* __restrict__ gh, float* __restrict__ gi,
    float* __restrict__ logp)
{
    int idx = blockIdx.x * 256 + threadIdx.x;  // 5455872 total
    if (idx < 65536) { t0[idx] = map_b[idx & 1023]; return; }
    idx -= 65536;
    if (idx < 65536) { a1b[idx] = ai_b[idx & 1023]; return; }
    idx -= 65536;
    if (idx < 65536) { a2b[idx] = ah_b[idx & 1023]; return; }
    idx -= 65536;
    if (idx < 65536) { attnb[idx] = ao_b[idx & 1023]; return; }
    idx -= 65536;
    if (idx < 1572864) {
        const int layer = idx / 196608, col = idx % 3072;
        gh[idx] = gru_bhh[layer * 3072 + col];
        return;
    }
    idx -= 1572864;
    if (idx < 1572864) {
        const int layer = idx / 196608, col = idx % 3072;
        gi[idx] = gru_bih[layer * 3072 + col];
        return;
    }
    idx -= 1572864;
    if (idx < 2048000) logp[idx] = out_b[idx % 32000];
}

// xe = relu(emb[x])  -> [64,1024] fp32
__global__ __launch_bounds__(256) void gather_relu(
    const float* __restrict__ emb, const int* __restrict__ xidx,
    float* __restrict__ xe)
{
    const int gid = blockIdx.x * 256 + threadIdx.x;  // 65536 total
    const int m = gid >> 10, e = gid & 1023;
    xe[gid] = fmaxf(emb[(long long)xidx[m] * 1024 + e], 0.0f);
}

// h[i] = hiddens[i] + relu(attnb)  -> [8,64,1024] fp32
__global__ __launch_bounds__(256) void hsum(
    const float* __restrict__ hiddens, const float* __restrict__ attn,
    float* __restrict__ h)
{
    const int gid = blockIdx.x * 256 + threadIdx.x;  // 524288 total
    h[gid] = hiddens[gid] + fmaxf(attn[gid & 65535], 0.0f);
}

// GRU pointwise; writes cell output (and h1 copy for c==0) and next input
__global__ __launch_bounds__(256) void gru_pw(
    const float* __restrict__ gi, const float* __restrict__ gh,
    const float* __restrict__ h, const float* __restrict__ oprev,
    float* __restrict__ o_out, float* __restrict__ o_out2,
    float* __restrict__ xin_next)
{
    const int gid = blockIdx.x * 256 + threadIdx.x;  // 65536 total
    const int m = gid >> 10, nn = gid & 1023;
    const long long gb = (long long)m * 3072 + nn;
    const float i_r = gi[gb], i_z = gi[gb + 1024], i_n = gi[gb + 2048];
    const float h_r = gh[gb], h_z = gh[gb + 1024], h_n = gh[gb + 2048];
    const float r = 1.0f / (1.0f + __expf(-(i_r + h_r)));
    const float z = 1.0f / (1.0f + __expf(-(i_z + h_z)));
    const float nv = tanhf(i_n + r * h_n);
    const float x = (1.0f - z) * nv + z * h[gid];
    o_out[gid] = x;
    if (o_out2) o_out2[gid] = x;
    float xi = x;
    if (oprev) xi += oprev[gid];
    xin_next[gid] = xi;
}

// per-row logsumexp over [64,32000] fp32 logits (in d_out), float4 loads
__global__ __launch_bounds__(256) void rowstats(
    const float* __restrict__ logits, float* __restrict__ stats)
{
    const int m = blockIdx.x;
    const f32x4* row = reinterpret_cast<const f32x4*>(logits + (long long)m * 32000);
    __shared__ float red[256];
    const int tid = threadIdx.x;
    float mx = -1e30f;
    for (int i = tid; i < 8000; i += 256) {
        f32x4 v = row[i];
        mx = fmaxf(mx, fmaxf(fmaxf(v[0], v[1]), fmaxf(v[2], v[3])));
    }
    red[tid] = mx;
    __syncthreads();
    for (int off = 128; off > 0; off >>= 1) {
        if (tid < off) red[tid] = fmaxf(red[tid], red[tid + off]);
        __syncthreads();
    }
    mx = red[0];
    __syncthreads();
    float s = 0.0f;
    for (int i = tid; i < 8000; i += 256) {
        f32x4 v = row[i];
        s += __expf(v[0] - mx) + __expf(v[1] - mx) + __expf(v[2] - mx) + __expf(v[3] - mx);
    }
    red[tid] = s;
    __syncthreads();
    for (int off = 128; off > 0; off >>= 1) {
        if (tid < off) red[tid] += red[tid + off];
        __syncthreads();
    }
    if (tid == 0) stats[m] = mx + logf(red[0]);
}

// in-place: logp = logits - stats[m]
__global__ __launch_bounds__(256) void logp_k(
    float* __restrict__ out, const float* __restrict__ stats)
{
    const int n = blockIdx.x * 256 + threadIdx.x;  // gridDim.x = 125
    const int m = blockIdx.y;
    const long long idx = (long long)m * 32000 + n;
    out[idx] = out[idx] - stats[m];
}

extern "C" void kernel_launch(void* const* d_in, const int* in_sizes, int n_in,
                              void* d_out, int out_size, void* d_ws, size_t ws_size,
                              hipStream_t stream)
{
    const float* feature   = (const float*)d_in[0];   // [64,2048]
    const int*   x         = (const int*)d_in[1];     // [64]
    const float* attention = (const float*)d_in[2];   // [64,1024]
    const float* hiddens   = (const float*)d_in[3];   // [8,64,1024]
    const float* emb       = (const float*)d_in[4];   // [32000,1024]
    const float* map_W     = (const float*)d_in[5];   // [1024,2048]
    const float* map_b     = (const float*)d_in[6];
    const float* ai_W      = (const float*)d_in[7];
    const float* ai_b      = (const float*)d_in[8];
    const float* ah_W      = (const float*)d_in[9];
    const float* ah_b      = (const float*)d_in[10];
    const float* ao_W      = (const float*)d_in[11];
    const float* ao_b      = (const float*)d_in[12];
    const float* gru_Wih   = (const float*)d_in[13];  // [8,3072,1024]
    const float* gru_Whh   = (const float*)d_in[14];  // [8,3072,1024]
    const float* gru_bih   = (const float*)d_in[15];  // [8,3072]
    const float* gru_bhh   = (const float*)d_in[16];  // [8,3072]
    const float* out_W     = (const float*)d_in[17];  // [32000,1024]
    const float* out_b     = (const float*)d_in[18];  // [32000]

    float* out      = (float*)d_out;
    float* out_logp = out;                    // [64,32000]
    float* out_h1   = out + 2048000;          // [64,1024]
    float* out_nh   = out + 2048000 + 65536;  // [8,64,1024]

    float* w = (float*)d_ws;                  // element offsets
    float* xin   = w + 0;        // [64,1024]
    float* t0    = w + 65536;
    float* a1b   = w + 131072;
    float* a2b   = w + 196608;
    float* attnb = w + 262144;
    float* hbuf  = w + 327680;   // [8,64,1024]
    float* gh    = w + 851968;   // [8,64,3072]
    float* gi    = w + 2424832;  // [8,64,3072]
    float* stats = w + 3997696;  // [64]

    // bias pre-init of all accumulators
    init_acc<<<21312, 256, 0, stream>>>(map_b, ai_b, ah_b, ao_b,
                                        gru_bhh, gru_bih, out_b,
                                        t0, a1b, a2b, attnb, gh, gi, out_logp);
    // xe = relu(emb[x])
    gather_relu<<<256, 256, 0, stream>>>(emb, x, xin);

    // t0 += feature @ map_W.T   (K=2048, 16 chunks of 128)
    gemm_acc<0><<<dim3(64, 16, 1), 64, 0, stream>>>(feature, 0, map_W, 0, nullptr,
                                                    t0, 0, 2048, 128, 1024);
    // ai GEMM: A' = relu(t0) + attention  (matches ref: feat+attention, no 2nd relu)
    gemm_acc<2><<<dim3(64, 8, 1), 64, 0, stream>>>(t0, 0, ai_W, 0, attention,
                                                   a1b, 0, 1024, 128, 1024);
    // ah / ao GEMMs: plain relu between stages (matches ref)
    gemm_acc<1><<<dim3(64, 8, 1), 64, 0, stream>>>(a1b, 0, ah_W, 0, nullptr,
                                                   a2b, 0, 1024, 128, 1024);
    gemm_acc<1><<<dim3(64, 8, 1), 64, 0, stream>>>(a2b, 0, ao_W, 0, nullptr,
                                                   attnb, 0, 1024, 128, 1024);

    // h[i] = hiddens[i] + relu(attn)
    hsum<<<2048, 256, 0, stream>>>(hiddens, attnb, hbuf);

    // batched gh[i] += h[i] @ Whh[i].T   (8 layers x 2 k-chunks)
    gemm_acc<0><<<dim3(192, 2, 8), 64, 0, stream>>>(hbuf, 65536, gru_Whh, 3145728,
                                                    nullptr, gh, 196608,
                                                    1024, 512, 3072);

    // sequential GRU chain (gi k-split 8-way: 1536 waves per GEMM)
    for (int c = 0; c < 8; ++c) {
        gemm_acc<0><<<dim3(192, 8, 1), 64, 0, stream>>>(
            xin, 0, gru_Wih + (long long)c * 3145728, 0, nullptr,
            gi + (long long)c * 196608, 0, 1024, 128, 3072);
        gru_pw<<<256, 256, 0, stream>>>(
            gi + (long long)c * 196608, gh + (long long)c * 196608,
            hbuf + (long long)c * 65536,
            (c >= 2) ? out_nh + (long long)(c - 1) * 65536 : nullptr,
            out_nh + (long long)c * 65536,
            (c == 0) ? out_h1 : nullptr,
            xin);
    }

    // logits += x8 @ out_W.T   (2000 n-tiles x 2 k-chunks)
    gemm_acc<0><<<dim3(2000, 2, 1), 64, 0, stream>>>(out_nh + 7LL * 65536, 0,
                                                     out_W, 0, nullptr,
                                                     out_logp, 0, 1024, 512, 32000);

    // log_softmax in place
    rowstats<<<64, 256, 0, stream>>>(out_logp, stats);
    logp_k<<<dim3(125, 64), 256, 0, stream>>>(out_logp, stats);
}